// Round 2
// baseline (12697.139 us; speedup 1.0000x reference)
//
#include <hip/hip_runtime.h>
#include <hip/hip_bf16.h>
#include <math.h>

typedef __bf16 bf16x8 __attribute__((ext_vector_type(8)));
typedef float f32x4 __attribute__((ext_vector_type(4)));
typedef unsigned int u32;
typedef u32 u32x4 __attribute__((ext_vector_type(4)));
typedef unsigned short u16;

#define BATCH 1024
#define DDIM  512
#define HID   1024
#define NELEM (BATCH*DDIM)
#define TOLF  1e-3f
#define NITER 48

// Dormand-Prince tableau
#define CA31 (3.0f/40.0f)
#define CA32 (9.0f/40.0f)
#define CA41 (44.0f/45.0f)
#define CA42 (-56.0f/15.0f)
#define CA43 (32.0f/9.0f)
#define CA51 (19372.0f/6561.0f)
#define CA52 (-25360.0f/2187.0f)
#define CA53 (64448.0f/6561.0f)
#define CA54 (-212.0f/729.0f)
#define CA61 (9017.0f/3168.0f)
#define CA62 (-355.0f/33.0f)
#define CA63 (46732.0f/5247.0f)
#define CA64 (49.0f/176.0f)
#define CA65 (-5103.0f/18656.0f)
#define CB1  (35.0f/384.0f)
#define CB3  (500.0f/1113.0f)
#define CB4  (125.0f/192.0f)
#define CB5  (-2187.0f/6784.0f)
#define CB6  (11.0f/84.0f)
#define CE1  (71.0f/57600.0f)
#define CE3  (-71.0f/16695.0f)
#define CE4  (71.0f/1920.0f)
#define CE5  (-17253.0f/339200.0f)
#define CE6  (22.0f/525.0f)
#define CE7  (-1.0f/40.0f)

__device__ __forceinline__ u16 f2b(float f) {
    u32 u = __builtin_bit_cast(u32, f);
    u32 r = (u + 0x7fffu + ((u >> 16) & 1u)) >> 16;
    return (u16)r;
}

// ---------------- prep: transpose weights to bf16, init y/arg/scalars -------
__global__ void prep_kernel(const float* __restrict__ x,
                            const float* __restrict__ W1,
                            const float* __restrict__ W2,
                            u16* __restrict__ W1T, u16* __restrict__ W2T,
                            float* __restrict__ Y, u16* __restrict__ ARG,
                            float* __restrict__ SC) {
    int i0 = blockIdx.x * blockDim.x + threadIdx.x;
    int stride = gridDim.x * blockDim.x;
    // W1T[n][k] = bf16(W1[k][n]), n<HID, k<DDIM
    for (int i = i0; i < HID * DDIM; i += stride) {
        int n = i / DDIM, k = i % DDIM;
        W1T[i] = f2b(W1[(size_t)k * HID + n]);
    }
    // W2T[n][h] = bf16(W2[h][n]), n<DDIM, h<HID
    for (int i = i0; i < DDIM * HID; i += stride) {
        int n = i / HID, h = i % HID;
        W2T[i] = f2b(W2[(size_t)h * DDIM + n]);
    }
    for (int i = i0; i < NELEM; i += stride) {
        float v = x[i];
        Y[i] = v;
        ARG[i] = f2b(v);
    }
    if (i0 == 0) {
        SC[0] = 0.0f;   // t
        SC[1] = 0.05f;  // dt
        SC[2] = 0.05f;  // dt_c = min(dt, 1-t)
        SC[3] = 0.0f;   // upd flag
    }
}

// ---------------- GEMM with fused epilogues --------------------------------
enum { EPI_TANH = 0, EPI_KINIT, EPI_K2, EPI_K3, EPI_K4, EPI_K5, EPI_K6, EPI_K7 };

struct GP {
    const u16* A;      // (M x K) bf16 row-major
    const u16* BT;     // (N x K) bf16 row-major (pre-transposed B)
    const float* bias; // (N)
    int K;             // 512 or 1024
    int N;             // ldc
    u16* outB;         // bf16 out (TANH: H ; K2..K5: next arg ; K6: y5 bf16)
    float* outF;       // f32 out (k_s)
    float* y5f;        // y5 f32 (written by K6, read by K7)
    const float* y;
    const float* k1; const float* k2; const float* k3;
    const float* k4; const float* k5; const float* k6;
    const float* sc;   // scalars
    float* errparts;   // 128 partial sums (K7)
};

template <int EPI>
__global__ __launch_bounds__(256)
void gemm_bt(GP p) {
    __shared__ __align__(16) u16 lA[64][72];
    __shared__ __align__(16) u16 lB[64][72];
    const int tid = threadIdx.x;
    const int lane = tid & 63;
    const int wave = tid >> 6;
    const int wm = wave >> 1, wn = wave & 1;
    const int mBase = blockIdx.y * 64, nBase = blockIdx.x * 64;
    const int K = p.K, N = p.N;

    f32x4 acc[2][2] = {};

    for (int kt = 0; kt < K; kt += 64) {
        // stage A and BT tiles (64x64 bf16 each) into padded LDS
#pragma unroll
        for (int i = 0; i < 2; i++) {
            int chunk = tid + i * 256;        // 0..511
            int r = chunk >> 3;               // 0..63
            int c8 = (chunk & 7) * 8;         // 0..56
            const u16* ga = p.A + (size_t)(mBase + r) * K + kt + c8;
            *(u32x4*)&lA[r][c8] = *(const u32x4*)ga;
            const u16* gb = p.BT + (size_t)(nBase + r) * K + kt + c8;
            *(u32x4*)&lB[r][c8] = *(const u32x4*)gb;
        }
        __syncthreads();
#pragma unroll
        for (int ks = 0; ks < 2; ks++) {
            const int kk = ks * 32 + (lane >> 4) * 8;
            bf16x8 av[2], bv[2];
#pragma unroll
            for (int mi = 0; mi < 2; mi++)
                av[mi] = __builtin_bit_cast(bf16x8, *(const u32x4*)&lA[wm * 32 + mi * 16 + (lane & 15)][kk]);
#pragma unroll
            for (int ni = 0; ni < 2; ni++)
                bv[ni] = __builtin_bit_cast(bf16x8, *(const u32x4*)&lB[wn * 32 + ni * 16 + (lane & 15)][kk]);
#pragma unroll
            for (int mi = 0; mi < 2; mi++)
#pragma unroll
                for (int ni = 0; ni < 2; ni++)
                    acc[mi][ni] = __builtin_amdgcn_mfma_f32_16x16x32_bf16(av[mi], bv[ni], acc[mi][ni], 0, 0, 0);
        }
        __syncthreads();
    }

    // ---------- epilogue ----------
    float dtc = 0.0f;
    if (EPI >= EPI_K2) dtc = p.sc[2];
    float lsum = 0.0f;

#pragma unroll
    for (int mi = 0; mi < 2; mi++)
#pragma unroll
        for (int ni = 0; ni < 2; ni++) {
#pragma unroll
            for (int r = 0; r < 4; r++) {
                const int row = mBase + wm * 32 + mi * 16 + (lane >> 4) * 4 + r;
                const int col = nBase + wn * 32 + ni * 16 + (lane & 15);
                const size_t idx = (size_t)row * N + col;
                float val = acc[mi][ni][r] + p.bias[col];
                if (EPI == EPI_TANH) {
                    p.outB[idx] = f2b(tanhf(val));
                } else if (EPI == EPI_KINIT) {
                    p.outF[idx] = val;
                } else if (EPI == EPI_K2) {
                    p.outF[idx] = val;
                    float a = p.y[idx] + dtc * (CA31 * p.k1[idx] + CA32 * val);
                    p.outB[idx] = f2b(a);
                } else if (EPI == EPI_K3) {
                    p.outF[idx] = val;
                    float a = p.y[idx] + dtc * (CA41 * p.k1[idx] + CA42 * p.k2[idx] + CA43 * val);
                    p.outB[idx] = f2b(a);
                } else if (EPI == EPI_K4) {
                    p.outF[idx] = val;
                    float a = p.y[idx] + dtc * (CA51 * p.k1[idx] + CA52 * p.k2[idx]
                                                + CA53 * p.k3[idx] + CA54 * val);
                    p.outB[idx] = f2b(a);
                } else if (EPI == EPI_K5) {
                    p.outF[idx] = val;
                    float a = p.y[idx] + dtc * (CA61 * p.k1[idx] + CA62 * p.k2[idx]
                                                + CA63 * p.k3[idx] + CA64 * p.k4[idx] + CA65 * val);
                    p.outB[idx] = f2b(a);
                } else if (EPI == EPI_K6) {
                    p.outF[idx] = val;  // k6
                    float y5v = p.y[idx] + dtc * (CB1 * p.k1[idx] + CB3 * p.k3[idx]
                                                  + CB4 * p.k4[idx] + CB5 * p.k5[idx] + CB6 * val);
                    p.y5f[idx] = y5v;
                    p.outB[idx] = f2b(y5v);
                } else if (EPI == EPI_K7) {
                    p.outF[idx] = val;  // k7
                    float errv = dtc * (CE1 * p.k1[idx] + CE3 * p.k3[idx] + CE4 * p.k4[idx]
                                        + CE5 * p.k5[idx] + CE6 * p.k6[idx] + CE7 * val);
                    float yv = p.y[idx], y5v = p.y5f[idx];
                    float scl = TOLF + TOLF * fmaxf(fabsf(yv), fabsf(y5v));
                    float rr = errv / scl;
                    lsum += rr * rr;
                }
            }
        }

    if (EPI == EPI_K7) {
#pragma unroll
        for (int off = 32; off; off >>= 1) lsum += __shfl_down(lsum, off);
        __shared__ float wpart[4];
        if (lane == 0) wpart[wave] = lsum;
        __syncthreads();
        if (tid == 0)
            p.errparts[blockIdx.y * gridDim.x + blockIdx.x] = wpart[0] + wpart[1] + wpart[2] + wpart[3];
    }
}

// ---------------- scalar controller ----------------------------------------
__global__ void scalar_step(float* __restrict__ SC, const float* __restrict__ parts, int nparts) {
    if (threadIdx.x == 0 && blockIdx.x == 0) {
        float es = 0.0f;
        for (int i = 0; i < nparts; i++) es += parts[i];
        float t = SC[0], dt = SC[1], dtc = SC[2];
        float en = fmaxf(sqrtf(es / (float)NELEM), 1e-10f);
        bool done = (t >= 1.0f);
        bool accept = (en <= 1.0f);
        bool upd = accept && !done;
        float fac = fminf(fmaxf(0.9f * powf(en, -0.2f), 0.2f), 10.0f);
        float tn = upd ? t + dtc : t;
        float dtn = done ? dt : dtc * fac;
        SC[0] = tn;
        SC[1] = dtn;
        SC[2] = fminf(dtn, 1.0f - tn);
        SC[3] = upd ? 1.0f : 0.0f;
    }
}

// ---------------- commit: select y/k1, build next stage-2 arg ---------------
template <bool SEL>
__global__ void commit_k(float* __restrict__ Y, const float* __restrict__ Y5,
                         float* __restrict__ K1, const float* __restrict__ K7b,
                         u16* __restrict__ ARG, const float* __restrict__ SC) {
    const float dtc = SC[2];
    const bool upd = SEL && (SC[3] > 0.5f);
    int i0 = blockIdx.x * blockDim.x + threadIdx.x;
    int stride = gridDim.x * blockDim.x;
    for (int i = i0; i < NELEM; i += stride) {
        float yv, k1v;
        if (upd) {
            yv = Y5[i]; k1v = K7b[i];
            Y[i] = yv; K1[i] = k1v;
        } else {
            yv = Y[i]; k1v = K1[i];
        }
        ARG[i] = f2b(yv + dtc * 0.2f * k1v);
    }
}

// ---------------- launch ----------------------------------------------------
extern "C" void kernel_launch(void* const* d_in, const int* in_sizes, int n_in,
                              void* d_out, int out_size, void* d_ws, size_t ws_size,
                              hipStream_t stream) {
    const float* x  = (const float*)d_in[0];
    const float* W1 = (const float*)d_in[1];
    const float* b1 = (const float*)d_in[2];
    const float* W2 = (const float*)d_in[3];
    const float* b2 = (const float*)d_in[4];

    char* w = (char*)d_ws;
    auto alloc = [&](size_t bytes) -> void* {
        void* q = (void*)w;
        w += (bytes + 255) & ~(size_t)255;
        return q;
    };
    u16* W1T = (u16*)alloc((size_t)HID * DDIM * 2);
    u16* W2T = (u16*)alloc((size_t)DDIM * HID * 2);
    u16* Hb  = (u16*)alloc((size_t)BATCH * HID * 2);
    u16* ARG = (u16*)alloc((size_t)NELEM * 2);
    float* Y   = (float*)alloc((size_t)NELEM * 4);
    float* Y5  = (float*)alloc((size_t)NELEM * 4);
    float* K1  = (float*)alloc((size_t)NELEM * 4);
    float* K2  = (float*)alloc((size_t)NELEM * 4);
    float* K3  = (float*)alloc((size_t)NELEM * 4);
    float* K4  = (float*)alloc((size_t)NELEM * 4);
    float* K5  = (float*)alloc((size_t)NELEM * 4);
    float* K6  = (float*)alloc((size_t)NELEM * 4);
    float* K7  = (float*)alloc((size_t)NELEM * 4);
    float* SC    = (float*)alloc(256);
    float* PARTS = (float*)alloc(128 * 4);

    prep_kernel<<<1024, 256, 0, stream>>>(x, W1, W2, W1T, W2T, Y, ARG, SC);

    GP g1{};
    g1.A = ARG; g1.BT = W1T; g1.bias = b1; g1.K = DDIM; g1.N = HID;
    g1.outB = Hb; g1.sc = SC;

    GP g2{};
    g2.A = Hb; g2.BT = W2T; g2.bias = b2; g2.K = HID; g2.N = DDIM;
    g2.outB = ARG; g2.y5f = Y5;
    g2.y = Y; g2.k1 = K1; g2.k2 = K2; g2.k3 = K3; g2.k4 = K4; g2.k5 = K5; g2.k6 = K6;
    g2.sc = SC; g2.errparts = PARTS;

    const dim3 grid1(HID / 64, BATCH / 64);   // 16 x 16
    const dim3 grid2(DDIM / 64, BATCH / 64);  // 8 x 16

    // initial k1 = f(y0)
    gemm_bt<EPI_TANH><<<grid1, 256, 0, stream>>>(g1);
    {
        GP gi = g2; gi.outF = K1;
        gemm_bt<EPI_KINIT><<<grid2, 256, 0, stream>>>(gi);
    }
    commit_k<false><<<512, 256, 0, stream>>>(Y, Y5, K1, K7, ARG, SC);

    for (int it = 0; it < NITER; it++) {
        GP g = g2;
        gemm_bt<EPI_TANH><<<grid1, 256, 0, stream>>>(g1);
        g.outF = K2; gemm_bt<EPI_K2><<<grid2, 256, 0, stream>>>(g);
        gemm_bt<EPI_TANH><<<grid1, 256, 0, stream>>>(g1);
        g.outF = K3; gemm_bt<EPI_K3><<<grid2, 256, 0, stream>>>(g);
        gemm_bt<EPI_TANH><<<grid1, 256, 0, stream>>>(g1);
        g.outF = K4; gemm_bt<EPI_K4><<<grid2, 256, 0, stream>>>(g);
        gemm_bt<EPI_TANH><<<grid1, 256, 0, stream>>>(g1);
        g.outF = K5; gemm_bt<EPI_K5><<<grid2, 256, 0, stream>>>(g);
        gemm_bt<EPI_TANH><<<grid1, 256, 0, stream>>>(g1);
        g.outF = K6; gemm_bt<EPI_K6><<<grid2, 256, 0, stream>>>(g);
        gemm_bt<EPI_TANH><<<grid1, 256, 0, stream>>>(g1);  // consumes y5 bf16
        g.outF = K7; gemm_bt<EPI_K7><<<grid2, 256, 0, stream>>>(g);
        scalar_step<<<1, 64, 0, stream>>>(SC, PARTS, 128);
        commit_k<true><<<512, 256, 0, stream>>>(Y, Y5, K1, K7, ARG, SC);
    }

    hipMemcpyAsync(d_out, Y, (size_t)NELEM * sizeof(float), hipMemcpyDeviceToDevice, stream);
}